// Round 6
// baseline (860.394 us; speedup 1.0000x reference)
//
#include <hip/hip_runtime.h>

#define NN 10000
#define CC 16
#define CAP 96     // max nnz/row; E[nnz]=33, sigma~5.7 -> ~11 sigma headroom; 96%16==0
#define RPB 16     // rows per block in step kernel (RPB*CC == 256 threads)
#define NBLK 625   // NN / RPB
#define CSRB 2500  // CSR build blocks (4 rows each), +1 mask-detect block
#define AGT __HIP_MEMORY_SCOPE_AGENT

// native LLVM vector type: binds to a VGPR quad in inline asm ("v"),
// unlike HIP's float4 struct (passed indirectly -> constraint error).
typedef float v4f __attribute__((ext_vector_type(4)));

// ---- coherent (sc1, L3-point-of-coherence) scalar access helpers ---------
static __device__ __forceinline__ float ld_coh(const float* p) {
    return __hip_atomic_load((float*)p, __ATOMIC_RELAXED, AGT);
}
static __device__ __forceinline__ void st_coh(float* p, float v) {
    __hip_atomic_store(p, v, __ATOMIC_RELAXED, AGT);
}
// 16B coherent store (q==0 lanes): row = one 64B line, owned by one block ->
// no cross-writer false sharing. Barrier's vmcnt drain orders it.
static __device__ __forceinline__ void st_coh4(float* p, v4f v) {
    asm volatile("global_store_dwordx4 %0, %1, off sc0 sc1" :: "v"(p), "v"(v) : "memory");
}
// 4 coherent 16B gathers batched behind one waitcnt: 4-deep MLP, 4 classes
// per op. Early-clobber outs so async data return can't alias addr regs.
static __device__ __forceinline__ void gather4_coh(
        const float* p0, const float* p1, const float* p2, const float* p3,
        v4f& y0, v4f& y1, v4f& y2, v4f& y3) {
    asm volatile(
        "global_load_dwordx4 %0, %4, off sc0 sc1\n\t"
        "global_load_dwordx4 %1, %5, off sc0 sc1\n\t"
        "global_load_dwordx4 %2, %6, off sc0 sc1\n\t"
        "global_load_dwordx4 %3, %7, off sc0 sc1\n\t"
        "s_waitcnt vmcnt(0)"
        : "=&v"(y0), "=&v"(y1), "=&v"(y2), "=&v"(y3)
        : "v"(p0), "v"(p1), "v"(p2), "v"(p3)
        : "memory");
}

// ---- pure-relaxed spin barrier (no wbl2/inv; explicit vmcnt drain) -------
static __device__ __forceinline__ void gbar(int* slot) {
    __syncthreads();
    if (threadIdx.x == 0) {
        asm volatile("s_waitcnt vmcnt(0)" ::: "memory");
        __hip_atomic_fetch_add(slot, 1, __ATOMIC_RELAXED, AGT);
        while (__hip_atomic_load(slot, __ATOMIC_RELAXED, AGT) != NBLK)
            __builtin_amdgcn_s_sleep(4);
    }
    __syncthreads();
}

// ---- train_mask storage-format-agnostic accessor -------------------------
// mode 0: int32 0/1, mode 1: uint8 bool, mode 2: float32 0.0/1.0
__device__ __forceinline__ bool mask_at(const void* p, int i, int mode) {
    if (mode == 0) return ((const int*)p)[i] != 0;
    if (mode == 1) return ((const unsigned char*)p)[i] != 0;
    return ((const float*)p)[i] != 0.0f;
}

// ===========================================================================
// K1 (normal launch, 2501 blocks): balanced CSR build, 4 rows/block, into a
// q-TRANSPOSED pack: slot p of a row stored at [row*96 + (p&3)*24 + (p>>2)].
// Step threads (q = c&3) then read their k=q+4m entries as contiguous 32B.
// Zero-filled buckets double as the n16 pad (weight 0 => contributes 0).
// ===========================================================================
__global__ __launch_bounds__(256) void build_csr_t(const float* __restrict__ adj,
                                                   int2* __restrict__ pack,
                                                   int* __restrict__ cnt,
                                                   const unsigned int* __restrict__ mask_words,
                                                   int* __restrict__ flag) {
    if (blockIdx.x == CSRB) {      // mask storage-mode detect
        __shared__ int s_ib, s_fb;
        if (threadIdx.x == 0) { s_ib = 0; s_fb = 0; }
        __syncthreads();
        int ib = 0, fb = 0;
        for (int i = threadIdx.x; i < NN / 4; i += 256) {
            unsigned w = mask_words[i];
            ib |= (w > 1u);
            fb |= (w != 0u && w != 0x3F800000u);
        }
        if (ib) s_ib = 1;
        if (fb) s_fb = 1;
        __syncthreads();
        if (threadIdx.x == 0) *flag = s_ib ? (s_fb ? 1 : 2) : 0;
        return;
    }
    __shared__ int  s_cnt[4];
    __shared__ int2 s_p[4 * CAP];  // transposed within each row's 96 slots
    const int row0 = blockIdx.x * 4;
    for (int i = threadIdx.x; i < 4 * CAP; i += 256) s_p[i] = make_int2(0, 0);
    if (threadIdx.x < 4) s_cnt[threadIdx.x] = 0;
    __syncthreads();
    for (int idx = threadIdx.x; idx < 4 * (NN / 4); idx += 256) {
        int r = idx / (NN / 4);
        int i = idx - r * (NN / 4);
        float4 v = ((const float4*)(adj + (size_t)(row0 + r) * NN))[i];
        int j = i * 4;
        if (v.x != 0.f) { int p = atomicAdd(&s_cnt[r], 1); if (p < CAP) s_p[r * CAP + (p & 3) * 24 + (p >> 2)] = make_int2((j    ) * CC, __float_as_int(v.x)); }
        if (v.y != 0.f) { int p = atomicAdd(&s_cnt[r], 1); if (p < CAP) s_p[r * CAP + (p & 3) * 24 + (p >> 2)] = make_int2((j + 1) * CC, __float_as_int(v.y)); }
        if (v.z != 0.f) { int p = atomicAdd(&s_cnt[r], 1); if (p < CAP) s_p[r * CAP + (p & 3) * 24 + (p >> 2)] = make_int2((j + 2) * CC, __float_as_int(v.z)); }
        if (v.w != 0.f) { int p = atomicAdd(&s_cnt[r], 1); if (p < CAP) s_p[r * CAP + (p & 3) * 24 + (p >> 2)] = make_int2((j + 3) * CC, __float_as_int(v.w)); }
    }
    __syncthreads();
    if (threadIdx.x < 4) cnt[row0 + threadIdx.x] = s_cnt[threadIdx.x] < CAP ? s_cnt[threadIdx.x] : CAP;
    for (int i = threadIdx.x; i < 4 * CAP; i += 256) pack[(size_t)row0 * CAP + i] = s_p[i];
}

// ===========================================================================
// K2 (cooperative, 625 blocks): steps 1..10 + hardening + loss + reduce.
// Thread (row, c): q = c&3 handles nonzeros k ≡ q (mod 4), 4 classes cg4=c&12
// per 16B gather; width-4 shuffle butterfly recombines; q==0 lane stores 16B.
// ===========================================================================
__global__ __launch_bounds__(256, 3) void lp_steps(
        const int2* __restrict__ pack,
        const int* __restrict__ cnt,
        const float* __restrict__ labels,
        const float* __restrict__ pseudo,
        const float* __restrict__ gumbel,
        const void*  __restrict__ tmask,
        const int*   __restrict__ flag,
        float* __restrict__ Ya,
        float* __restrict__ Yb,
        float* __restrict__ partial,
        float* __restrict__ out,
        int*   __restrict__ bars)
{
    __shared__ float sw[4];
    __shared__ int s_last;

    const int b   = blockIdx.x;
    const int tid = threadIdx.x;
    const int lr  = tid >> 4;
    const int c   = tid & 15;
    const int row = b * RPB + lr;
    const int t   = row * CC + c;
    const int q   = c & 3;
    const int cg4 = c & 12;

    const int  mode = *flag;
    const int  n    = cnt[row];
    const int  n16  = (n + 15) & ~15;
    const int  rounds = n16 >> 4;          // 4 k-entries per q-thread per round
    const bool m    = mask_at(tmask, row, mode);
    const float lbl = labels[t];
    const v4f  lbl4 = *(const v4f*)(labels + (t & ~3));
    const int4* pp = (const int4*)(pack + (size_t)row * CAP + q * 24);

    // ---- step 1: Y1 = m ? labels : adj @ (mask ? labels : 0) -------------
    // labels is read-only input: plain cached loads.
    {
        v4f a4 = {0.f, 0.f, 0.f, 0.f};
        for (int r = 0; r < rounds; ++r) {
            int4 u0 = pp[2 * r], u1 = pp[2 * r + 1];
            #define ACC_LBL(ex, ew) { \
                float w_ = __int_as_float(ew); \
                if (w_ != 0.f && mask_at(tmask, (ex) >> 4, mode)) { \
                    v4f y_ = *(const v4f*)(labels + (ex) + cg4); \
                    a4.x = fmaf(w_, y_.x, a4.x); a4.y = fmaf(w_, y_.y, a4.y); \
                    a4.z = fmaf(w_, y_.z, a4.z); a4.w = fmaf(w_, y_.w, a4.w); } }
            ACC_LBL(u0.x, u0.y) ACC_LBL(u0.z, u0.w) ACC_LBL(u1.x, u1.y) ACC_LBL(u1.z, u1.w)
            #undef ACC_LBL
        }
        a4.x += __shfl_xor(a4.x, 1, 4); a4.x += __shfl_xor(a4.x, 2, 4);
        a4.y += __shfl_xor(a4.y, 1, 4); a4.y += __shfl_xor(a4.y, 2, 4);
        a4.z += __shfl_xor(a4.z, 1, 4); a4.z += __shfl_xor(a4.z, 2, 4);
        a4.w += __shfl_xor(a4.w, 1, 4); a4.w += __shfl_xor(a4.w, 2, 4);
        if (q == 0) {
            v4f o = m ? lbl4 : a4;
            st_coh4(&Ya[t], o);                // t aligned: c = cg4, q==0
        }
    }
    gbar(bars + 0);

    // ---- steps 2..9 ------------------------------------------------------
    float* cur = Ya;
    float* nxt = Yb;
    for (int it = 0; it < 8; ++it) {
        v4f a4 = {0.f, 0.f, 0.f, 0.f};
        for (int r = 0; r < rounds; ++r) {
            int4 u0 = pp[2 * r], u1 = pp[2 * r + 1];
            v4f y0, y1, y2, y3;
            gather4_coh(cur + u0.x + cg4, cur + u0.z + cg4,
                        cur + u1.x + cg4, cur + u1.z + cg4, y0, y1, y2, y3);
            float w0 = __int_as_float(u0.y), w1 = __int_as_float(u0.w);
            float w2 = __int_as_float(u1.y), w3 = __int_as_float(u1.w);
            a4.x = fmaf(w0, y0.x, a4.x); a4.y = fmaf(w0, y0.y, a4.y);
            a4.z = fmaf(w0, y0.z, a4.z); a4.w = fmaf(w0, y0.w, a4.w);
            a4.x = fmaf(w1, y1.x, a4.x); a4.y = fmaf(w1, y1.y, a4.y);
            a4.z = fmaf(w1, y1.z, a4.z); a4.w = fmaf(w1, y1.w, a4.w);
            a4.x = fmaf(w2, y2.x, a4.x); a4.y = fmaf(w2, y2.y, a4.y);
            a4.z = fmaf(w2, y2.z, a4.z); a4.w = fmaf(w2, y2.w, a4.w);
            a4.x = fmaf(w3, y3.x, a4.x); a4.y = fmaf(w3, y3.y, a4.y);
            a4.z = fmaf(w3, y3.z, a4.z); a4.w = fmaf(w3, y3.w, a4.w);
        }
        a4.x += __shfl_xor(a4.x, 1, 4); a4.x += __shfl_xor(a4.x, 2, 4);
        a4.y += __shfl_xor(a4.y, 1, 4); a4.y += __shfl_xor(a4.y, 2, 4);
        a4.z += __shfl_xor(a4.z, 1, 4); a4.z += __shfl_xor(a4.z, 2, 4);
        a4.w += __shfl_xor(a4.w, 1, 4); a4.w += __shfl_xor(a4.w, 2, 4);
        if (q == 0) {
            v4f o = m ? lbl4 : a4;
            st_coh4(&nxt[t], o);
        }
        gbar(bars + 1 + it);
        float* tmp = cur; cur = nxt; nxt = tmp;
    }

    // ---- step 10 + Gumbel straight-through hardening ---------------------
    {
        v4f a4 = {0.f, 0.f, 0.f, 0.f};
        for (int r = 0; r < rounds; ++r) {
            int4 u0 = pp[2 * r], u1 = pp[2 * r + 1];
            v4f y0, y1, y2, y3;
            gather4_coh(cur + u0.x + cg4, cur + u0.z + cg4,
                        cur + u1.x + cg4, cur + u1.z + cg4, y0, y1, y2, y3);
            float w0 = __int_as_float(u0.y), w1 = __int_as_float(u0.w);
            float w2 = __int_as_float(u1.y), w3 = __int_as_float(u1.w);
            a4.x = fmaf(w0, y0.x, a4.x); a4.y = fmaf(w0, y0.y, a4.y);
            a4.z = fmaf(w0, y0.z, a4.z); a4.w = fmaf(w0, y0.w, a4.w);
            a4.x = fmaf(w1, y1.x, a4.x); a4.y = fmaf(w1, y1.y, a4.y);
            a4.z = fmaf(w1, y1.z, a4.z); a4.w = fmaf(w1, y1.w, a4.w);
            a4.x = fmaf(w2, y2.x, a4.x); a4.y = fmaf(w2, y2.y, a4.y);
            a4.z = fmaf(w2, y2.z, a4.z); a4.w = fmaf(w2, y2.w, a4.w);
            a4.x = fmaf(w3, y3.x, a4.x); a4.y = fmaf(w3, y3.y, a4.y);
            a4.z = fmaf(w3, y3.z, a4.z); a4.w = fmaf(w3, y3.w, a4.w);
        }
        a4.x += __shfl_xor(a4.x, 1, 4); a4.x += __shfl_xor(a4.x, 2, 4);
        a4.y += __shfl_xor(a4.y, 1, 4); a4.y += __shfl_xor(a4.y, 2, 4);
        a4.z += __shfl_xor(a4.z, 1, 4); a4.z += __shfl_xor(a4.z, 2, 4);
        a4.w += __shfl_xor(a4.w, 1, 4); a4.w += __shfl_xor(a4.w, 2, 4);
        float acc = (q == 0) ? a4.x : (q == 1) ? a4.y : (q == 2) ? a4.z : a4.w;
        float y10 = m ? lbl : acc;
        float l = y10 + gumbel[t];                 // TAU = 1
        float mx = l;
        for (int off = 8; off >= 1; off >>= 1) mx = fmaxf(mx, __shfl_xor(mx, off, 16));
        float e_ = expf(l - mx);
        float s = e_;
        for (int off = 8; off >= 1; off >>= 1) s += __shfl_xor(s, off, 16);
        float soft = e_ / s;
        float hard = (l == mx) ? 1.0f : 0.0f;
        float y = (hard + soft) - soft;            // faithful ST forward
        float yo = m ? lbl : y;
        // pack 4 lanes' outputs into one 16B store on q==0
        float o1 = __shfl_xor(yo, 1, 4);
        float o2 = __shfl_xor(yo, 2, 4);
        float o3 = __shfl_xor(yo, 3, 4);
        if (q == 0) { v4f ov = {yo, o1, o2, o3}; st_coh4(&nxt[t], ov); }
    }
    gbar(bars + 9);
    const float* Y2 = nxt;

    // ---- dist = (adj!=0)@Y2, row-normalize, MSE per-block partial --------
    {
        v4f a4 = {0.f, 0.f, 0.f, 0.f};
        for (int r = 0; r < rounds; ++r) {
            int4 u0 = pp[2 * r], u1 = pp[2 * r + 1];
            v4f y0, y1, y2, y3;
            gather4_coh(Y2 + u0.x + cg4, Y2 + u0.z + cg4,
                        Y2 + u1.x + cg4, Y2 + u1.z + cg4, y0, y1, y2, y3);
            float g0 = (u0.y != 0) ? 1.f : 0.f, g1 = (u0.w != 0) ? 1.f : 0.f;
            float g2 = (u1.y != 0) ? 1.f : 0.f, g3 = (u1.w != 0) ? 1.f : 0.f;
            a4.x = fmaf(g0, y0.x, a4.x); a4.y = fmaf(g0, y0.y, a4.y);
            a4.z = fmaf(g0, y0.z, a4.z); a4.w = fmaf(g0, y0.w, a4.w);
            a4.x = fmaf(g1, y1.x, a4.x); a4.y = fmaf(g1, y1.y, a4.y);
            a4.z = fmaf(g1, y1.z, a4.z); a4.w = fmaf(g1, y1.w, a4.w);
            a4.x = fmaf(g2, y2.x, a4.x); a4.y = fmaf(g2, y2.y, a4.y);
            a4.z = fmaf(g2, y2.z, a4.z); a4.w = fmaf(g2, y2.w, a4.w);
            a4.x = fmaf(g3, y3.x, a4.x); a4.y = fmaf(g3, y3.y, a4.y);
            a4.z = fmaf(g3, y3.z, a4.z); a4.w = fmaf(g3, y3.w, a4.w);
        }
        a4.x += __shfl_xor(a4.x, 1, 4); a4.x += __shfl_xor(a4.x, 2, 4);
        a4.y += __shfl_xor(a4.y, 1, 4); a4.y += __shfl_xor(a4.y, 2, 4);
        a4.z += __shfl_xor(a4.z, 1, 4); a4.z += __shfl_xor(a4.z, 2, 4);
        a4.w += __shfl_xor(a4.w, 1, 4); a4.w += __shfl_xor(a4.w, 2, 4);
        float acc = (q == 0) ? a4.x : (q == 1) ? a4.y : (q == 2) ? a4.z : a4.w;
        float rs = acc;                            // row sum (diag -> rs > 0)
        for (int off = 8; off >= 1; off >>= 1) rs += __shfl_xor(rs, off, 16);
        float d = acc / rs - pseudo[t];
        float contrib = d * d * (1.0f / (NN * CC));
        for (int off = 32; off >= 1; off >>= 1) contrib += __shfl_down(contrib, off, 64);
        if ((tid & 63) == 0) sw[tid >> 6] = contrib;
        __syncthreads();
        if (tid == 0) {
            st_coh(&partial[b], sw[0] + sw[1] + sw[2] + sw[3]);
            asm volatile("s_waitcnt vmcnt(0)" ::: "memory");
            int old = __hip_atomic_fetch_add(bars + 15, 1, __ATOMIC_RELAXED, AGT);
            s_last = (old == NBLK - 1);
        }
        __syncthreads();
    }

    // ---- final reduce by last-arriving block -----------------------------
    if (s_last) {
        float s = 0.f;
        for (int i = tid; i < NBLK; i += 256) s += ld_coh(&partial[i]);
        for (int off = 32; off >= 1; off >>= 1) s += __shfl_down(s, off, 64);
        if ((tid & 63) == 0) sw[tid >> 6] = s;
        __syncthreads();
        if (tid == 0) out[0] = sw[0] + sw[1] + sw[2] + sw[3];
    }
}

// ===========================================================================
// Fallback chain (verified 629us 13-dispatch version) — only if cooperative
// launch is rejected. Uses its own (untransposed) pack layout.
// ===========================================================================
__global__ __launch_bounds__(256) void build_csr(const float* __restrict__ adj,
                                                 int2* __restrict__ pack,
                                                 int* __restrict__ cnt,
                                                 const unsigned int* __restrict__ mask_words,
                                                 int* __restrict__ flag) {
    if (blockIdx.x == NN) {
        __shared__ int s_int_bad, s_flt_bad;
        if (threadIdx.x == 0) { s_int_bad = 0; s_flt_bad = 0; }
        __syncthreads();
        for (int i = threadIdx.x; i < NN / 4; i += 256) {
            unsigned w = mask_words[i];
            if (w > 1u) s_int_bad = 1;
            if (w != 0u && w != 0x3F800000u) s_flt_bad = 1;
        }
        __syncthreads();
        if (threadIdx.x == 0) {
            int mode;
            if (!s_int_bad)      mode = 0;
            else if (!s_flt_bad) mode = 2;
            else                 mode = 1;
            *flag = mode;
        }
        return;
    }
    __shared__ int lcnt;
    const int row = blockIdx.x;
    if (threadIdx.x == 0) lcnt = 0;
    __syncthreads();
    const float4* rp = (const float4*)(adj + (size_t)row * NN);
    int2* pb = pack + (size_t)row * CAP;
    for (int i = threadIdx.x; i < NN / 4; i += 256) {
        float4 v = rp[i];
        int j = i * 4;
        if (v.x != 0.f) { int p = atomicAdd(&lcnt, 1); if (p < CAP) pb[p] = make_int2(j,     __float_as_int(v.x)); }
        if (v.y != 0.f) { int p = atomicAdd(&lcnt, 1); if (p < CAP) pb[p] = make_int2(j + 1, __float_as_int(v.y)); }
        if (v.z != 0.f) { int p = atomicAdd(&lcnt, 1); if (p < CAP) pb[p] = make_int2(j + 2, __float_as_int(v.z)); }
        if (v.w != 0.f) { int p = atomicAdd(&lcnt, 1); if (p < CAP) pb[p] = make_int2(j + 3, __float_as_int(v.w)); }
    }
    __syncthreads();
    if (threadIdx.x == 0) cnt[row] = (lcnt < CAP) ? lcnt : CAP;
}

__global__ __launch_bounds__(256) void spmv_first(const int2* __restrict__ pack,
                                                  const int* __restrict__ cnt,
                                                  const float* __restrict__ labels,
                                                  const void* __restrict__ tmask,
                                                  const int* __restrict__ flag,
                                                  float* __restrict__ Yout) {
    int t = blockIdx.x * 256 + threadIdx.x;
    int row = t >> 4, c = t & 15;
    int n = cnt[row];
    int mode = *flag;
    const int2* pp = pack + (size_t)row * CAP;
    float acc = 0.0f;
    #pragma unroll 4
    for (int k = 0; k < n; k++) {
        int2 e = pp[k];
        float yv = mask_at(tmask, e.x, mode) ? labels[e.x * CC + c] : 0.0f;
        acc = fmaf(__int_as_float(e.y), yv, acc);
    }
    bool m = mask_at(tmask, row, mode);
    Yout[t] = m ? labels[t] : acc;
}

__global__ __launch_bounds__(256) void spmv_step(const int2* __restrict__ pack,
                                                 const int* __restrict__ cnt,
                                                 const float* __restrict__ Yin,
                                                 const float* __restrict__ labels,
                                                 const void* __restrict__ tmask,
                                                 const int* __restrict__ flag,
                                                 float* __restrict__ Yout) {
    int t = blockIdx.x * 256 + threadIdx.x;
    int row = t >> 4, c = t & 15;
    int n = cnt[row];
    const int2* pp = pack + (size_t)row * CAP;
    float acc = 0.0f;
    #pragma unroll 4
    for (int k = 0; k < n; k++) {
        int2 e = pp[k];
        acc = fmaf(__int_as_float(e.y), Yin[e.x * CC + c], acc);
    }
    bool m = mask_at(tmask, row, *flag);
    Yout[t] = m ? labels[t] : acc;
}

__global__ __launch_bounds__(256) void spmv_harden(const int2* __restrict__ pack,
                                                   const int* __restrict__ cnt,
                                                   const float* __restrict__ Yin,
                                                   const float* __restrict__ labels,
                                                   const float* __restrict__ gumbel,
                                                   const void* __restrict__ tmask,
                                                   const int* __restrict__ flag,
                                                   float* __restrict__ Yout) {
    int t = blockIdx.x * 256 + threadIdx.x;
    int row = t >> 4, c = t & 15;
    int n = cnt[row];
    const int2* pp = pack + (size_t)row * CAP;
    float acc = 0.0f;
    #pragma unroll 4
    for (int k = 0; k < n; k++) {
        int2 e = pp[k];
        acc = fmaf(__int_as_float(e.y), Yin[e.x * CC + c], acc);
    }
    bool m = mask_at(tmask, row, *flag);
    float lbl = labels[t];
    float y10 = m ? lbl : acc;
    float l = y10 + gumbel[t];
    float mx = l;
    for (int off = 8; off >= 1; off >>= 1) mx = fmaxf(mx, __shfl_xor(mx, off, 16));
    float e = expf(l - mx);
    float s = e;
    for (int off = 8; off >= 1; off >>= 1) s += __shfl_xor(s, off, 16);
    float soft = e / s;
    float hard = (l == mx) ? 1.0f : 0.0f;
    float y = (hard + soft) - soft;
    Yout[t] = m ? lbl : y;
}

__global__ __launch_bounds__(256) void mask_spmv_loss(const int2* __restrict__ pack,
                                                      const int* __restrict__ cnt,
                                                      const float* __restrict__ Y2,
                                                      const float* __restrict__ pseudo,
                                                      float* __restrict__ partial) {
    int t = blockIdx.x * 256 + threadIdx.x;
    int row = t >> 4, c = t & 15;
    int n = cnt[row];
    const int2* pp = pack + (size_t)row * CAP;
    float acc = 0.0f;
    #pragma unroll 4
    for (int k = 0; k < n; k++) acc += Y2[pp[k].x * CC + c];
    float rs = acc;
    for (int off = 8; off >= 1; off >>= 1) rs += __shfl_xor(rs, off, 16);
    float d = acc / rs - pseudo[t];
    float contrib = d * d * (1.0f / (NN * CC));
    for (int off = 32; off >= 1; off >>= 1) contrib += __shfl_down(contrib, off, 64);
    __shared__ float sw[4];
    if ((threadIdx.x & 63) == 0) sw[threadIdx.x >> 6] = contrib;
    __syncthreads();
    if (threadIdx.x == 0) partial[blockIdx.x] = sw[0] + sw[1] + sw[2] + sw[3];
}

__global__ void final_reduce(const float* __restrict__ partial, float* __restrict__ out) {
    float s = 0.0f;
    for (int i = threadIdx.x; i < NBLK; i += 256) s += partial[i];
    for (int off = 32; off >= 1; off >>= 1) s += __shfl_down(s, off, 64);
    __shared__ float sw[4];
    if ((threadIdx.x & 63) == 0) sw[threadIdx.x >> 6] = s;
    __syncthreads();
    if (threadIdx.x == 0) out[0] = sw[0] + sw[1] + sw[2] + sw[3];
}

extern "C" void kernel_launch(void* const* d_in, const int* in_sizes, int n_in,
                              void* d_out, int out_size, void* d_ws, size_t ws_size,
                              hipStream_t stream) {
    const float* adj    = (const float*)d_in[0];
    const float* labels = (const float*)d_in[1];
    const float* pseudo = (const float*)d_in[2];
    const float* gumbel = (const float*)d_in[3];
    const void*  tmask  = d_in[4];
    // d_in[5] = iter_step (10), d_in[6] = k_hop (1): fixed scalars in setup.

    char* ws = (char*)d_ws;
    int*   flag    = (int*)(ws + 0);                 // 64 B
    int*   cnt     = (int*)(ws + 64);                // 40,000 B
    int2*  pack    = (int2*)(ws + 40064);            // 7,680,000 B (16B-aligned)
    float* Ya      = (float*)(ws + 7720064);         // 640,000 B
    float* Yb      = (float*)(ws + 8360064);         // 640,000 B
    float* partial = (float*)(ws + 9000064);         // 2,500 B (end 9,002,564)
    int*   bars    = (int*)(ws + 9002624);           // 128 B barrier state

    float* outp = (float*)d_out;

    (void)hipMemsetAsync(bars, 0, 128, stream);      // capture-safe tiny memset

    // K1: balanced CSR build (normal launch), K2: cooperative step phase.
    build_csr_t<<<CSRB + 1, 256, 0, stream>>>(adj, pack, cnt,
                                              (const unsigned int*)tmask, flag);

    void* args[] = { (void*)&pack, (void*)&cnt, (void*)&labels, (void*)&pseudo,
                     (void*)&gumbel, (void*)&tmask, (void*)&flag,
                     (void*)&Ya, (void*)&Yb, (void*)&partial,
                     (void*)&outp, (void*)&bars };
    hipError_t err = hipLaunchCooperativeKernel((void*)lp_steps, dim3(NBLK), dim3(256),
                                                args, 0, stream);
    if (err == hipSuccess) return;
    (void)hipGetLastError();                         // clear sticky error, run fallback

    build_csr<<<NN + 1, 256, 0, stream>>>(adj, pack, cnt, (const unsigned int*)tmask, flag);
    spmv_first<<<NBLK, 256, 0, stream>>>(pack, cnt, labels, tmask, flag, Ya);
    float* cur = Ya;
    float* nxt = Yb;
    for (int it = 0; it < 8; ++it) {
        spmv_step<<<NBLK, 256, 0, stream>>>(pack, cnt, cur, labels, tmask, flag, nxt);
        float* tmp = cur; cur = nxt; nxt = tmp;
    }
    spmv_harden<<<NBLK, 256, 0, stream>>>(pack, cnt, cur, labels, gumbel, tmask, flag, nxt);
    mask_spmv_loss<<<NBLK, 256, 0, stream>>>(pack, cnt, nxt, pseudo, partial);
    final_reduce<<<1, 256, 0, stream>>>(partial, outp);
}

// Round 10
// 662.103 us; speedup vs baseline: 1.2995x; 1.2995x over previous
//
#include <hip/hip_runtime.h>

#define NN 10000
#define CC 16
#define CAP 96     // max nnz/row; E[nnz]=33, sigma~5.7 -> ~11 sigma headroom; 96%16==0
#define WPB 64     // rows per block in step kernel (WPB*CC == 1024 threads)
#define NB2 157    // ceil(NN/WPB) cooperative grid
#define NLEAF 16   // barrier tree fanout
#define RPB 16     // fallback chain rows/block
#define NBLK 625   // fallback chain grid
#define CSRB 2500  // CSR build blocks (4 rows each), +1 mask-detect block
#define AGT __HIP_MEMORY_SCOPE_AGENT

// native LLVM vector type: binds to a VGPR quad in inline asm ("v")
typedef float v4f __attribute__((ext_vector_type(4)));

// ---- coherent (sc1, L3-point-of-coherence) scalar access helpers ---------
static __device__ __forceinline__ float ld_coh(const float* p) {
    return __hip_atomic_load((float*)p, __ATOMIC_RELAXED, AGT);
}
static __device__ __forceinline__ void st_coh(float* p, float v) {
    __hip_atomic_store(p, v, __ATOMIC_RELAXED, AGT);
}
static __device__ __forceinline__ void st_coh4(float* p, v4f v) {
    asm volatile("global_store_dwordx4 %0, %1, off sc0 sc1" :: "v"(p), "v"(v) : "memory");
}
// 8 coherent 16B gathers batched behind ONE waitcnt: 8-deep MLP.
static __device__ __forceinline__ void gather8_coh(
        const float* p0, const float* p1, const float* p2, const float* p3,
        const float* p4, const float* p5, const float* p6, const float* p7,
        v4f& y0, v4f& y1, v4f& y2, v4f& y3,
        v4f& y4, v4f& y5, v4f& y6, v4f& y7) {
    asm volatile(
        "global_load_dwordx4 %0, %8, off sc0 sc1\n\t"
        "global_load_dwordx4 %1, %9, off sc0 sc1\n\t"
        "global_load_dwordx4 %2, %10, off sc0 sc1\n\t"
        "global_load_dwordx4 %3, %11, off sc0 sc1\n\t"
        "global_load_dwordx4 %4, %12, off sc0 sc1\n\t"
        "global_load_dwordx4 %5, %13, off sc0 sc1\n\t"
        "global_load_dwordx4 %6, %14, off sc0 sc1\n\t"
        "global_load_dwordx4 %7, %15, off sc0 sc1\n\t"
        "s_waitcnt vmcnt(0)"
        : "=&v"(y0), "=&v"(y1), "=&v"(y2), "=&v"(y3),
          "=&v"(y4), "=&v"(y5), "=&v"(y6), "=&v"(y7)
        : "v"(p0), "v"(p1), "v"(p2), "v"(p3),
          "v"(p4), "v"(p5), "v"(p6), "v"(p7)
        : "memory");
}

// ---- two-level barrier: 16 leaf counters (own 128B lines) -> root ->
// separated release flag. Arrival lines see only RMWs (fast chain, parallel
// across TCC channels); spinners poll only the release line (read-only).
// Monotone: fresh counters per barrier, no reset. bars zeroed pre-launch.
// Layout (int idx, 32-int = 128B stride): barrier k: leaf l at (k*18+l)*32,
// root at (k*18+16)*32, release at (k*18+17)*32. Final arriver ctr: k=10.
static __device__ __forceinline__ void gbar2(int* bars, int k, int leaf, int leafSz) {
    __syncthreads();
    if (threadIdx.x == 0) {
        int* base = bars + k * 18 * 32;
        asm volatile("s_waitcnt vmcnt(0)" ::: "memory");   // Y stores done at L3
        int old = __hip_atomic_fetch_add(base + leaf * 32, 1, __ATOMIC_RELAXED, AGT);
        if (old == leafSz - 1) {
            int r = __hip_atomic_fetch_add(base + 16 * 32, 1, __ATOMIC_RELAXED, AGT);
            if (r == NLEAF - 1)
                __hip_atomic_store(base + 17 * 32, 1, __ATOMIC_RELAXED, AGT);
        }
        while (__hip_atomic_load(base + 17 * 32, __ATOMIC_RELAXED, AGT) == 0)
            __builtin_amdgcn_s_sleep(8);
    }
    __syncthreads();
}

// ---- train_mask storage-format-agnostic accessor -------------------------
// mode 0: int32 0/1, mode 1: uint8 bool, mode 2: float32 0.0/1.0
__device__ __forceinline__ bool mask_at(const void* p, int i, int mode) {
    if (mode == 0) return ((const int*)p)[i] != 0;
    if (mode == 1) return ((const unsigned char*)p)[i] != 0;
    return ((const float*)p)[i] != 0.0f;
}

// ===========================================================================
// K1 (normal launch, 2501 blocks): balanced CSR build, 4 rows/block, into a
// q-TRANSPOSED pack: slot p of a row at [row*96 + (p&3)*24 + (p>>2)].
// Zero-filled slots double as pad (weight 0 => contributes 0).
// ===========================================================================
__global__ __launch_bounds__(256) void build_csr_t(const float* __restrict__ adj,
                                                   int2* __restrict__ pack,
                                                   int* __restrict__ cnt,
                                                   const unsigned int* __restrict__ mask_words,
                                                   int* __restrict__ flag) {
    if (blockIdx.x == CSRB) {      // mask storage-mode detect
        __shared__ int s_ib, s_fb;
        if (threadIdx.x == 0) { s_ib = 0; s_fb = 0; }
        __syncthreads();
        int ib = 0, fb = 0;
        for (int i = threadIdx.x; i < NN / 4; i += 256) {
            unsigned w = mask_words[i];
            ib |= (w > 1u);
            fb |= (w != 0u && w != 0x3F800000u);
        }
        if (ib) s_ib = 1;
        if (fb) s_fb = 1;
        __syncthreads();
        if (threadIdx.x == 0) *flag = s_ib ? (s_fb ? 1 : 2) : 0;
        return;
    }
    __shared__ int  s_cnt[4];
    __shared__ int2 s_p[4 * CAP];
    const int row0 = blockIdx.x * 4;
    for (int i = threadIdx.x; i < 4 * CAP; i += 256) s_p[i] = make_int2(0, 0);
    if (threadIdx.x < 4) s_cnt[threadIdx.x] = 0;
    __syncthreads();
    for (int idx = threadIdx.x; idx < 4 * (NN / 4); idx += 256) {
        int r = idx / (NN / 4);
        int i = idx - r * (NN / 4);
        float4 v = ((const float4*)(adj + (size_t)(row0 + r) * NN))[i];
        int j = i * 4;
        if (v.x != 0.f) { int p = atomicAdd(&s_cnt[r], 1); if (p < CAP) s_p[r * CAP + (p & 3) * 24 + (p >> 2)] = make_int2((j    ) * CC, __float_as_int(v.x)); }
        if (v.y != 0.f) { int p = atomicAdd(&s_cnt[r], 1); if (p < CAP) s_p[r * CAP + (p & 3) * 24 + (p >> 2)] = make_int2((j + 1) * CC, __float_as_int(v.y)); }
        if (v.z != 0.f) { int p = atomicAdd(&s_cnt[r], 1); if (p < CAP) s_p[r * CAP + (p & 3) * 24 + (p >> 2)] = make_int2((j + 2) * CC, __float_as_int(v.z)); }
        if (v.w != 0.f) { int p = atomicAdd(&s_cnt[r], 1); if (p < CAP) s_p[r * CAP + (p & 3) * 24 + (p >> 2)] = make_int2((j + 3) * CC, __float_as_int(v.w)); }
    }
    __syncthreads();
    if (threadIdx.x < 4) cnt[row0 + threadIdx.x] = s_cnt[threadIdx.x] < CAP ? s_cnt[threadIdx.x] : CAP;
    for (int i = threadIdx.x; i < 4 * CAP; i += 256) pack[(size_t)row0 * CAP + i] = s_p[i];
}

// ===========================================================================
// K2 (cooperative, 157 blocks x 1024): steps 1..10 + hardening + loss.
// Thread (row, c): q = c&3 handles k ≡ q (mod 4); cg4 = c&12 class offset.
// ===========================================================================
__global__ __launch_bounds__(1024, 4) void lp_steps(
        const int2* __restrict__ pack,
        const int* __restrict__ cnt,
        const float* __restrict__ labels,
        const float* __restrict__ pseudo,
        const float* __restrict__ gumbel,
        const void*  __restrict__ tmask,
        const int*   __restrict__ flag,
        float* __restrict__ Ya,
        float* __restrict__ Yb,
        float* __restrict__ partial,
        float* __restrict__ out,
        int*   __restrict__ bars)
{
    __shared__ float sw[16];
    __shared__ int s_last;

    const int b   = blockIdx.x;
    const int tid = threadIdx.x;
    const int lr  = tid >> 4;
    const int c   = tid & 15;
    const int row = b * WPB + lr;
    const bool valid = (row < NN);
    const int t   = valid ? row * CC + c : 0;
    const int q   = c & 3;
    const int cg4 = c & 12;
    const int leaf   = b & 15;
    const int leafSz = 9 + (leaf < 13 ? 1 : 0);   // 13*10 + 3*9 = 157

    const int  mode = *flag;
    const int  n    = valid ? cnt[row] : 0;
    const int  rounds = ((n + 15) & ~15) >> 4;
    const int  pairs  = (rounds + 1) >> 1;        // gather8 covers 2 rounds
    const bool m    = valid ? mask_at(tmask, row, mode) : false;
    const float lbl = valid ? labels[t] : 0.f;
    v4f lbl4 = {0.f,0.f,0.f,0.f};
    if (valid && q == 0) lbl4 = *(const v4f*)(labels + t);
    const int4* pp = (const int4*)(pack + (size_t)(valid ? row : 0) * CAP + q * 24);

    // 32-fma accumulate helper over one gather8 result
    #define ACC8(W0,W1,W2,W3,W4,W5,W6,W7) \
        a4.x = fmaf(W0, y0.x, a4.x); a4.y = fmaf(W0, y0.y, a4.y); a4.z = fmaf(W0, y0.z, a4.z); a4.w = fmaf(W0, y0.w, a4.w); \
        a4.x = fmaf(W1, y1.x, a4.x); a4.y = fmaf(W1, y1.y, a4.y); a4.z = fmaf(W1, y1.z, a4.z); a4.w = fmaf(W1, y1.w, a4.w); \
        a4.x = fmaf(W2, y2.x, a4.x); a4.y = fmaf(W2, y2.y, a4.y); a4.z = fmaf(W2, y2.z, a4.z); a4.w = fmaf(W2, y2.w, a4.w); \
        a4.x = fmaf(W3, y3.x, a4.x); a4.y = fmaf(W3, y3.y, a4.y); a4.z = fmaf(W3, y3.z, a4.z); a4.w = fmaf(W3, y3.w, a4.w); \
        a4.x = fmaf(W4, y4.x, a4.x); a4.y = fmaf(W4, y4.y, a4.y); a4.z = fmaf(W4, y4.z, a4.z); a4.w = fmaf(W4, y4.w, a4.w); \
        a4.x = fmaf(W5, y5.x, a4.x); a4.y = fmaf(W5, y5.y, a4.y); a4.z = fmaf(W5, y5.z, a4.z); a4.w = fmaf(W5, y5.w, a4.w); \
        a4.x = fmaf(W6, y6.x, a4.x); a4.y = fmaf(W6, y6.y, a4.y); a4.z = fmaf(W6, y6.z, a4.z); a4.w = fmaf(W6, y6.w, a4.w); \
        a4.x = fmaf(W7, y7.x, a4.x); a4.y = fmaf(W7, y7.y, a4.y); a4.z = fmaf(W7, y7.z, a4.z); a4.w = fmaf(W7, y7.w, a4.w);

    #define BFLY4(v_) \
        v_.x += __shfl_xor(v_.x, 1, 4); v_.x += __shfl_xor(v_.x, 2, 4); \
        v_.y += __shfl_xor(v_.y, 1, 4); v_.y += __shfl_xor(v_.y, 2, 4); \
        v_.z += __shfl_xor(v_.z, 1, 4); v_.z += __shfl_xor(v_.z, 2, 4); \
        v_.w += __shfl_xor(v_.w, 1, 4); v_.w += __shfl_xor(v_.w, 2, 4);

    // ---- step 1: Y1 = m ? labels : adj @ (mask ? labels : 0) -------------
    {
        v4f a4 = {0.f, 0.f, 0.f, 0.f};
        for (int r = 0; r < rounds; ++r) {
            int4 u0 = pp[2 * r], u1 = pp[2 * r + 1];
            #define ACC_LBL(ex, ew) { \
                float w_ = __int_as_float(ew); \
                if (w_ != 0.f && mask_at(tmask, (ex) >> 4, mode)) { \
                    v4f y_ = *(const v4f*)(labels + (ex) + cg4); \
                    a4.x = fmaf(w_, y_.x, a4.x); a4.y = fmaf(w_, y_.y, a4.y); \
                    a4.z = fmaf(w_, y_.z, a4.z); a4.w = fmaf(w_, y_.w, a4.w); } }
            ACC_LBL(u0.x, u0.y) ACC_LBL(u0.z, u0.w) ACC_LBL(u1.x, u1.y) ACC_LBL(u1.z, u1.w)
            #undef ACC_LBL
        }
        BFLY4(a4)
        if (valid && q == 0) { v4f o = m ? lbl4 : a4; st_coh4(&Ya[t], o); }
    }
    gbar2(bars, 0, leaf, leafSz);

    // ---- steps 2..9 ------------------------------------------------------
    float* cur = Ya;
    float* nxt = Yb;
    for (int it = 0; it < 8; ++it) {
        v4f a4 = {0.f, 0.f, 0.f, 0.f};
        for (int r2 = 0; r2 < pairs; ++r2) {
            int4 u0 = pp[4*r2], u1 = pp[4*r2+1], u2 = pp[4*r2+2], u3 = pp[4*r2+3];
            v4f y0, y1, y2, y3, y4, y5, y6, y7;
            gather8_coh(cur + u0.x + cg4, cur + u0.z + cg4,
                        cur + u1.x + cg4, cur + u1.z + cg4,
                        cur + u2.x + cg4, cur + u2.z + cg4,
                        cur + u3.x + cg4, cur + u3.z + cg4,
                        y0, y1, y2, y3, y4, y5, y6, y7);
            ACC8(__int_as_float(u0.y), __int_as_float(u0.w),
                 __int_as_float(u1.y), __int_as_float(u1.w),
                 __int_as_float(u2.y), __int_as_float(u2.w),
                 __int_as_float(u3.y), __int_as_float(u3.w))
        }
        BFLY4(a4)
        if (valid && q == 0) { v4f o = m ? lbl4 : a4; st_coh4(&nxt[t], o); }
        gbar2(bars, 1 + it, leaf, leafSz);
        float* tmp = cur; cur = nxt; nxt = tmp;
    }

    // ---- step 10 + Gumbel straight-through hardening ---------------------
    {
        v4f a4 = {0.f, 0.f, 0.f, 0.f};
        for (int r2 = 0; r2 < pairs; ++r2) {
            int4 u0 = pp[4*r2], u1 = pp[4*r2+1], u2 = pp[4*r2+2], u3 = pp[4*r2+3];
            v4f y0, y1, y2, y3, y4, y5, y6, y7;
            gather8_coh(cur + u0.x + cg4, cur + u0.z + cg4,
                        cur + u1.x + cg4, cur + u1.z + cg4,
                        cur + u2.x + cg4, cur + u2.z + cg4,
                        cur + u3.x + cg4, cur + u3.z + cg4,
                        y0, y1, y2, y3, y4, y5, y6, y7);
            ACC8(__int_as_float(u0.y), __int_as_float(u0.w),
                 __int_as_float(u1.y), __int_as_float(u1.w),
                 __int_as_float(u2.y), __int_as_float(u2.w),
                 __int_as_float(u3.y), __int_as_float(u3.w))
        }
        BFLY4(a4)
        float acc = (q == 0) ? a4.x : (q == 1) ? a4.y : (q == 2) ? a4.z : a4.w;
        float y10 = m ? lbl : acc;
        float l = y10 + (valid ? gumbel[t] : 0.f);     // TAU = 1
        float mx = l;
        for (int off = 8; off >= 1; off >>= 1) mx = fmaxf(mx, __shfl_xor(mx, off, 16));
        float e_ = expf(l - mx);
        float s = e_;
        for (int off = 8; off >= 1; off >>= 1) s += __shfl_xor(s, off, 16);
        float soft = e_ / s;
        float hard = (l == mx) ? 1.0f : 0.0f;
        float y = (hard + soft) - soft;                // faithful ST forward
        float yo = m ? lbl : y;
        float o1 = __shfl_xor(yo, 1, 4);
        float o2 = __shfl_xor(yo, 2, 4);
        float o3 = __shfl_xor(yo, 3, 4);
        if (valid && q == 0) { v4f ov = {yo, o1, o2, o3}; st_coh4(&nxt[t], ov); }
    }
    gbar2(bars, 9, leaf, leafSz);
    const float* Y2 = nxt;

    // ---- dist = (adj!=0)@Y2, row-normalize, MSE per-block partial --------
    {
        v4f a4 = {0.f, 0.f, 0.f, 0.f};
        for (int r2 = 0; r2 < pairs; ++r2) {
            int4 u0 = pp[4*r2], u1 = pp[4*r2+1], u2 = pp[4*r2+2], u3 = pp[4*r2+3];
            v4f y0, y1, y2, y3, y4, y5, y6, y7;
            gather8_coh(Y2 + u0.x + cg4, Y2 + u0.z + cg4,
                        Y2 + u1.x + cg4, Y2 + u1.z + cg4,
                        Y2 + u2.x + cg4, Y2 + u2.z + cg4,
                        Y2 + u3.x + cg4, Y2 + u3.z + cg4,
                        y0, y1, y2, y3, y4, y5, y6, y7);
            ACC8((u0.y != 0) ? 1.f : 0.f, (u0.w != 0) ? 1.f : 0.f,
                 (u1.y != 0) ? 1.f : 0.f, (u1.w != 0) ? 1.f : 0.f,
                 (u2.y != 0) ? 1.f : 0.f, (u2.w != 0) ? 1.f : 0.f,
                 (u3.y != 0) ? 1.f : 0.f, (u3.w != 0) ? 1.f : 0.f)
        }
        BFLY4(a4)
        float acc = (q == 0) ? a4.x : (q == 1) ? a4.y : (q == 2) ? a4.z : a4.w;
        float rs = acc;                                // diag -> rs > 0
        for (int off = 8; off >= 1; off >>= 1) rs += __shfl_xor(rs, off, 16);
        float d = valid ? (acc / rs - pseudo[t]) : 0.f;
        float contrib = d * d * (1.0f / (NN * CC));
        for (int off = 32; off >= 1; off >>= 1) contrib += __shfl_down(contrib, off, 64);
        if ((tid & 63) == 0) sw[tid >> 6] = contrib;
        __syncthreads();
        if (tid == 0) {
            float ps = 0.f;
            #pragma unroll
            for (int i = 0; i < 16; ++i) ps += sw[i];
            st_coh(&partial[b], ps);
            asm volatile("s_waitcnt vmcnt(0)" ::: "memory");
            int old = __hip_atomic_fetch_add(bars + 10 * 18 * 32, 1, __ATOMIC_RELAXED, AGT);
            s_last = (old == NB2 - 1);
        }
        __syncthreads();
    }

    // ---- final reduce by last-arriving block -----------------------------
    if (s_last) {
        float s = 0.f;
        for (int i = tid; i < NB2; i += 1024) s += ld_coh(&partial[i]);
        for (int off = 32; off >= 1; off >>= 1) s += __shfl_down(s, off, 64);
        if ((tid & 63) == 0) sw[tid >> 6] = s;
        __syncthreads();
        if (tid == 0) {
            float ts = 0.f;
            #pragma unroll
            for (int i = 0; i < 16; ++i) ts += sw[i];
            out[0] = ts;
        }
    }
    #undef ACC8
    #undef BFLY4
}

// ===========================================================================
// Fallback chain (verified 629us 13-dispatch version) — only if cooperative
// launch is rejected. Uses its own (untransposed) pack layout.
// ===========================================================================
__global__ __launch_bounds__(256) void build_csr(const float* __restrict__ adj,
                                                 int2* __restrict__ pack,
                                                 int* __restrict__ cnt,
                                                 const unsigned int* __restrict__ mask_words,
                                                 int* __restrict__ flag) {
    if (blockIdx.x == NN) {
        __shared__ int s_int_bad, s_flt_bad;
        if (threadIdx.x == 0) { s_int_bad = 0; s_flt_bad = 0; }
        __syncthreads();
        for (int i = threadIdx.x; i < NN / 4; i += 256) {
            unsigned w = mask_words[i];
            if (w > 1u) s_int_bad = 1;
            if (w != 0u && w != 0x3F800000u) s_flt_bad = 1;
        }
        __syncthreads();
        if (threadIdx.x == 0) {
            int mode;
            if (!s_int_bad)      mode = 0;
            else if (!s_flt_bad) mode = 2;
            else                 mode = 1;
            *flag = mode;
        }
        return;
    }
    __shared__ int lcnt;
    const int row = blockIdx.x;
    if (threadIdx.x == 0) lcnt = 0;
    __syncthreads();
    const float4* rp = (const float4*)(adj + (size_t)row * NN);
    int2* pb = pack + (size_t)row * CAP;
    for (int i = threadIdx.x; i < NN / 4; i += 256) {
        float4 v = rp[i];
        int j = i * 4;
        if (v.x != 0.f) { int p = atomicAdd(&lcnt, 1); if (p < CAP) pb[p] = make_int2(j,     __float_as_int(v.x)); }
        if (v.y != 0.f) { int p = atomicAdd(&lcnt, 1); if (p < CAP) pb[p] = make_int2(j + 1, __float_as_int(v.y)); }
        if (v.z != 0.f) { int p = atomicAdd(&lcnt, 1); if (p < CAP) pb[p] = make_int2(j + 2, __float_as_int(v.z)); }
        if (v.w != 0.f) { int p = atomicAdd(&lcnt, 1); if (p < CAP) pb[p] = make_int2(j + 3, __float_as_int(v.w)); }
    }
    __syncthreads();
    if (threadIdx.x == 0) cnt[row] = (lcnt < CAP) ? lcnt : CAP;
}

__global__ __launch_bounds__(256) void spmv_first(const int2* __restrict__ pack,
                                                  const int* __restrict__ cnt,
                                                  const float* __restrict__ labels,
                                                  const void* __restrict__ tmask,
                                                  const int* __restrict__ flag,
                                                  float* __restrict__ Yout) {
    int t = blockIdx.x * 256 + threadIdx.x;
    int row = t >> 4, c = t & 15;
    int n = cnt[row];
    int mode = *flag;
    const int2* pp = pack + (size_t)row * CAP;
    float acc = 0.0f;
    #pragma unroll 4
    for (int k = 0; k < n; k++) {
        int2 e = pp[k];
        float yv = mask_at(tmask, e.x, mode) ? labels[e.x * CC + c] : 0.0f;
        acc = fmaf(__int_as_float(e.y), yv, acc);
    }
    bool m = mask_at(tmask, row, mode);
    Yout[t] = m ? labels[t] : acc;
}

__global__ __launch_bounds__(256) void spmv_step(const int2* __restrict__ pack,
                                                 const int* __restrict__ cnt,
                                                 const float* __restrict__ Yin,
                                                 const float* __restrict__ labels,
                                                 const void* __restrict__ tmask,
                                                 const int* __restrict__ flag,
                                                 float* __restrict__ Yout) {
    int t = blockIdx.x * 256 + threadIdx.x;
    int row = t >> 4, c = t & 15;
    int n = cnt[row];
    const int2* pp = pack + (size_t)row * CAP;
    float acc = 0.0f;
    #pragma unroll 4
    for (int k = 0; k < n; k++) {
        int2 e = pp[k];
        acc = fmaf(__int_as_float(e.y), Yin[e.x * CC + c], acc);
    }
    bool m = mask_at(tmask, row, *flag);
    Yout[t] = m ? labels[t] : acc;
}

__global__ __launch_bounds__(256) void spmv_harden(const int2* __restrict__ pack,
                                                   const int* __restrict__ cnt,
                                                   const float* __restrict__ Yin,
                                                   const float* __restrict__ labels,
                                                   const float* __restrict__ gumbel,
                                                   const void* __restrict__ tmask,
                                                   const int* __restrict__ flag,
                                                   float* __restrict__ Yout) {
    int t = blockIdx.x * 256 + threadIdx.x;
    int row = t >> 4, c = t & 15;
    int n = cnt[row];
    const int2* pp = pack + (size_t)row * CAP;
    float acc = 0.0f;
    #pragma unroll 4
    for (int k = 0; k < n; k++) {
        int2 e = pp[k];
        acc = fmaf(__int_as_float(e.y), Yin[e.x * CC + c], acc);
    }
    bool m = mask_at(tmask, row, *flag);
    float lbl = labels[t];
    float y10 = m ? lbl : acc;
    float l = y10 + gumbel[t];
    float mx = l;
    for (int off = 8; off >= 1; off >>= 1) mx = fmaxf(mx, __shfl_xor(mx, off, 16));
    float e = expf(l - mx);
    float s = e;
    for (int off = 8; off >= 1; off >>= 1) s += __shfl_xor(s, off, 16);
    float soft = e / s;
    float hard = (l == mx) ? 1.0f : 0.0f;
    float y = (hard + soft) - soft;
    Yout[t] = m ? lbl : y;
}

__global__ __launch_bounds__(256) void mask_spmv_loss(const int2* __restrict__ pack,
                                                      const int* __restrict__ cnt,
                                                      const float* __restrict__ Y2,
                                                      const float* __restrict__ pseudo,
                                                      float* __restrict__ partial) {
    int t = blockIdx.x * 256 + threadIdx.x;
    int row = t >> 4, c = t & 15;
    int n = cnt[row];
    const int2* pp = pack + (size_t)row * CAP;
    float acc = 0.0f;
    #pragma unroll 4
    for (int k = 0; k < n; k++) acc += Y2[pp[k].x * CC + c];
    float rs = acc;
    for (int off = 8; off >= 1; off >>= 1) rs += __shfl_xor(rs, off, 16);
    float d = acc / rs - pseudo[t];
    float contrib = d * d * (1.0f / (NN * CC));
    for (int off = 32; off >= 1; off >>= 1) contrib += __shfl_down(contrib, off, 64);
    __shared__ float sw[4];
    if ((threadIdx.x & 63) == 0) sw[threadIdx.x >> 6] = contrib;
    __syncthreads();
    if (threadIdx.x == 0) partial[blockIdx.x] = sw[0] + sw[1] + sw[2] + sw[3];
}

__global__ void final_reduce(const float* __restrict__ partial, float* __restrict__ out) {
    float s = 0.0f;
    for (int i = threadIdx.x; i < NBLK; i += 256) s += partial[i];
    for (int off = 32; off >= 1; off >>= 1) s += __shfl_down(s, off, 64);
    __shared__ float sw[4];
    if ((threadIdx.x & 63) == 0) sw[threadIdx.x >> 6] = s;
    __syncthreads();
    if (threadIdx.x == 0) out[0] = sw[0] + sw[1] + sw[2] + sw[3];
}

extern "C" void kernel_launch(void* const* d_in, const int* in_sizes, int n_in,
                              void* d_out, int out_size, void* d_ws, size_t ws_size,
                              hipStream_t stream) {
    const float* adj    = (const float*)d_in[0];
    const float* labels = (const float*)d_in[1];
    const float* pseudo = (const float*)d_in[2];
    const float* gumbel = (const float*)d_in[3];
    const void*  tmask  = d_in[4];
    // d_in[5] = iter_step (10), d_in[6] = k_hop (1): fixed scalars in setup.

    char* ws = (char*)d_ws;
    int*   flag    = (int*)(ws + 0);                 // 64 B
    int*   cnt     = (int*)(ws + 64);                // 40,000 B
    int2*  pack    = (int2*)(ws + 40064);            // 7,680,000 B (16B-aligned)
    float* Ya      = (float*)(ws + 7720064);         // 640,000 B
    float* Yb      = (float*)(ws + 8360064);         // 640,000 B
    float* partial = (float*)(ws + 9000064);         // 2,560 B
    int*   bars    = (int*)(ws + 9002624);           // 32 KB barrier state

    float* outp = (float*)d_out;

    (void)hipMemsetAsync(bars, 0, 32768, stream);    // capture-safe tiny memset

    // K1: balanced CSR build (normal launch), K2: cooperative step phase.
    build_csr_t<<<CSRB + 1, 256, 0, stream>>>(adj, pack, cnt,
                                              (const unsigned int*)tmask, flag);

    void* args[] = { (void*)&pack, (void*)&cnt, (void*)&labels, (void*)&pseudo,
                     (void*)&gumbel, (void*)&tmask, (void*)&flag,
                     (void*)&Ya, (void*)&Yb, (void*)&partial,
                     (void*)&outp, (void*)&bars };
    hipError_t err = hipLaunchCooperativeKernel((void*)lp_steps, dim3(NB2), dim3(1024),
                                                args, 0, stream);
    if (err == hipSuccess) return;
    (void)hipGetLastError();                         // clear sticky error, run fallback

    build_csr<<<NN + 1, 256, 0, stream>>>(adj, pack, cnt, (const unsigned int*)tmask, flag);
    spmv_first<<<NBLK, 256, 0, stream>>>(pack, cnt, labels, tmask, flag, Ya);
    float* cur = Ya;
    float* nxt = Yb;
    for (int it = 0; it < 8; ++it) {
        spmv_step<<<NBLK, 256, 0, stream>>>(pack, cnt, cur, labels, tmask, flag, nxt);
        float* tmp = cur; cur = nxt; nxt = tmp;
    }
    spmv_harden<<<NBLK, 256, 0, stream>>>(pack, cnt, cur, labels, gumbel, tmask, flag, nxt);
    mask_spmv_loss<<<NBLK, 256, 0, stream>>>(pack, cnt, nxt, pseudo, partial);
    final_reduce<<<1, 256, 0, stream>>>(partial, outp);
}

// Round 14
// 625.930 us; speedup vs baseline: 1.3746x; 1.0578x over previous
//
#include <hip/hip_runtime.h>

#define NN 10000
#define CC 16
#define CAP 96     // max nnz/row; E[nnz]=33, sigma~5.7 -> ~11 sigma headroom; 96%16==0
#define RPB 16     // rows per block in step kernels (RPB*CC == 256 threads)
#define NBLK 625   // NN / RPB
#define CSRB 2500  // CSR build blocks (4 rows each), +1 mask-detect block

// native LLVM vector type (16B loads/stores; compiler emits dwordx4)
typedef float v4f __attribute__((ext_vector_type(4)));

// ---- train_mask storage-format-agnostic accessor -------------------------
// mode 0: int32 0/1, mode 1: uint8 bool, mode 2: float32 0.0/1.0
__device__ __forceinline__ bool mask_at(const void* p, int i, int mode) {
    if (mode == 0) return ((const int*)p)[i] != 0;
    if (mode == 1) return ((const unsigned char*)p)[i] != 0;
    return ((const float*)p)[i] != 0.0f;
}

// ---- q-decomposed SpMV round accumulator (verified in rounds 6/10) -------
// Thread handles nonzeros k ≡ q (mod 4) of its row, 4 classes cg4..cg4+3.
// BINARY=false: weighted (adj @ Y); BINARY=true: (adj!=0) @ Y.
// Padded slots have w==0, col==0 -> contribute exactly 0 in both modes.
template<bool BINARY>
static __device__ __forceinline__ v4f acc_rounds(const int4* __restrict__ pp,
                                                 int pairs, int cg4,
                                                 const float* __restrict__ cur) {
    v4f a4 = {0.f, 0.f, 0.f, 0.f};
    for (int r2 = 0; r2 < pairs; ++r2) {
        int4 u0 = pp[4*r2], u1 = pp[4*r2+1], u2 = pp[4*r2+2], u3 = pp[4*r2+3];
        v4f y0 = *(const v4f*)(cur + u0.x + cg4);
        v4f y1 = *(const v4f*)(cur + u0.z + cg4);
        v4f y2 = *(const v4f*)(cur + u1.x + cg4);
        v4f y3 = *(const v4f*)(cur + u1.z + cg4);
        v4f y4 = *(const v4f*)(cur + u2.x + cg4);
        v4f y5 = *(const v4f*)(cur + u2.z + cg4);
        v4f y6 = *(const v4f*)(cur + u3.x + cg4);
        v4f y7 = *(const v4f*)(cur + u3.z + cg4);
        float w0, w1, w2, w3, w4, w5, w6, w7;
        if (BINARY) {
            w0 = (u0.y != 0) ? 1.f : 0.f; w1 = (u0.w != 0) ? 1.f : 0.f;
            w2 = (u1.y != 0) ? 1.f : 0.f; w3 = (u1.w != 0) ? 1.f : 0.f;
            w4 = (u2.y != 0) ? 1.f : 0.f; w5 = (u2.w != 0) ? 1.f : 0.f;
            w6 = (u3.y != 0) ? 1.f : 0.f; w7 = (u3.w != 0) ? 1.f : 0.f;
        } else {
            w0 = __int_as_float(u0.y); w1 = __int_as_float(u0.w);
            w2 = __int_as_float(u1.y); w3 = __int_as_float(u1.w);
            w4 = __int_as_float(u2.y); w5 = __int_as_float(u2.w);
            w6 = __int_as_float(u3.y); w7 = __int_as_float(u3.w);
        }
        a4.x = fmaf(w0, y0.x, a4.x); a4.y = fmaf(w0, y0.y, a4.y); a4.z = fmaf(w0, y0.z, a4.z); a4.w = fmaf(w0, y0.w, a4.w);
        a4.x = fmaf(w1, y1.x, a4.x); a4.y = fmaf(w1, y1.y, a4.y); a4.z = fmaf(w1, y1.z, a4.z); a4.w = fmaf(w1, y1.w, a4.w);
        a4.x = fmaf(w2, y2.x, a4.x); a4.y = fmaf(w2, y2.y, a4.y); a4.z = fmaf(w2, y2.z, a4.z); a4.w = fmaf(w2, y2.w, a4.w);
        a4.x = fmaf(w3, y3.x, a4.x); a4.y = fmaf(w3, y3.y, a4.y); a4.z = fmaf(w3, y3.z, a4.z); a4.w = fmaf(w3, y3.w, a4.w);
        a4.x = fmaf(w4, y4.x, a4.x); a4.y = fmaf(w4, y4.y, a4.y); a4.z = fmaf(w4, y4.z, a4.z); a4.w = fmaf(w4, y4.w, a4.w);
        a4.x = fmaf(w5, y5.x, a4.x); a4.y = fmaf(w5, y5.y, a4.y); a4.z = fmaf(w5, y5.z, a4.z); a4.w = fmaf(w5, y5.w, a4.w);
        a4.x = fmaf(w6, y6.x, a4.x); a4.y = fmaf(w6, y6.y, a4.y); a4.z = fmaf(w6, y6.z, a4.z); a4.w = fmaf(w6, y6.w, a4.w);
        a4.x = fmaf(w7, y7.x, a4.x); a4.y = fmaf(w7, y7.y, a4.y); a4.z = fmaf(w7, y7.z, a4.z); a4.w = fmaf(w7, y7.w, a4.w);
    }
    return a4;
}

static __device__ __forceinline__ void bfly4(v4f& v) {
    v.x += __shfl_xor(v.x, 1, 4); v.x += __shfl_xor(v.x, 2, 4);
    v.y += __shfl_xor(v.y, 1, 4); v.y += __shfl_xor(v.y, 2, 4);
    v.z += __shfl_xor(v.z, 1, 4); v.z += __shfl_xor(v.z, 2, 4);
    v.w += __shfl_xor(v.w, 1, 4); v.w += __shfl_xor(v.w, 2, 4);
}

// ===========================================================================
// K1 (2501 blocks): balanced CSR build, 4 rows/block, q-TRANSPOSED pack:
// slot p of a row at [row*96 + (p&3)*24 + (p>>2)]. Zero-filled slots = pad.
// (verified rounds 6/10)
// ===========================================================================
__global__ __launch_bounds__(256) void build_csr_t(const float* __restrict__ adj,
                                                   int2* __restrict__ pack,
                                                   int* __restrict__ cnt,
                                                   const unsigned int* __restrict__ mask_words,
                                                   int* __restrict__ flag) {
    if (blockIdx.x == CSRB) {      // mask storage-mode detect
        __shared__ int s_ib, s_fb;
        if (threadIdx.x == 0) { s_ib = 0; s_fb = 0; }
        __syncthreads();
        int ib = 0, fb = 0;
        for (int i = threadIdx.x; i < NN / 4; i += 256) {
            unsigned w = mask_words[i];
            ib |= (w > 1u);
            fb |= (w != 0u && w != 0x3F800000u);
        }
        if (ib) s_ib = 1;
        if (fb) s_fb = 1;
        __syncthreads();
        if (threadIdx.x == 0) *flag = s_ib ? (s_fb ? 1 : 2) : 0;
        return;
    }
    __shared__ int  s_cnt[4];
    __shared__ int2 s_p[4 * CAP];
    const int row0 = blockIdx.x * 4;
    for (int i = threadIdx.x; i < 4 * CAP; i += 256) s_p[i] = make_int2(0, 0);
    if (threadIdx.x < 4) s_cnt[threadIdx.x] = 0;
    __syncthreads();
    for (int idx = threadIdx.x; idx < 4 * (NN / 4); idx += 256) {
        int r = idx / (NN / 4);
        int i = idx - r * (NN / 4);
        float4 v = ((const float4*)(adj + (size_t)(row0 + r) * NN))[i];
        int j = i * 4;
        if (v.x != 0.f) { int p = atomicAdd(&s_cnt[r], 1); if (p < CAP) s_p[r * CAP + (p & 3) * 24 + (p >> 2)] = make_int2((j    ) * CC, __float_as_int(v.x)); }
        if (v.y != 0.f) { int p = atomicAdd(&s_cnt[r], 1); if (p < CAP) s_p[r * CAP + (p & 3) * 24 + (p >> 2)] = make_int2((j + 1) * CC, __float_as_int(v.y)); }
        if (v.z != 0.f) { int p = atomicAdd(&s_cnt[r], 1); if (p < CAP) s_p[r * CAP + (p & 3) * 24 + (p >> 2)] = make_int2((j + 2) * CC, __float_as_int(v.z)); }
        if (v.w != 0.f) { int p = atomicAdd(&s_cnt[r], 1); if (p < CAP) s_p[r * CAP + (p & 3) * 24 + (p >> 2)] = make_int2((j + 3) * CC, __float_as_int(v.w)); }
    }
    __syncthreads();
    if (threadIdx.x < 4) cnt[row0 + threadIdx.x] = s_cnt[threadIdx.x] < CAP ? s_cnt[threadIdx.x] : CAP;
    for (int i = threadIdx.x; i < 4 * CAP; i += 256) pack[(size_t)row0 * CAP + i] = s_p[i];
}

// ===========================================================================
// Step kernels (normal launch, 625 x 256): kernel boundary = barrier,
// plain cached loads (Y is L2-resident), q-decomposed + 16B vector access.
// ===========================================================================
__global__ __launch_bounds__(256) void spmv_first_t(const int2* __restrict__ pack,
                                                    const int* __restrict__ cnt,
                                                    const float* __restrict__ labels,
                                                    const void* __restrict__ tmask,
                                                    const int* __restrict__ flag,
                                                    float* __restrict__ Yout) {
    const int tid = threadIdx.x;
    const int row = blockIdx.x * RPB + (tid >> 4);
    const int c   = tid & 15;
    const int t   = row * CC + c;
    const int q   = c & 3;
    const int cg4 = c & 12;
    const int mode = *flag;
    const int n = cnt[row];
    const int rounds = ((n + 15) & ~15) >> 4;
    const int4* pp = (const int4*)(pack + (size_t)row * CAP + q * 24);

    v4f a4 = {0.f, 0.f, 0.f, 0.f};
    for (int r = 0; r < rounds; ++r) {
        int4 u0 = pp[2 * r], u1 = pp[2 * r + 1];
        #define ACC_LBL(ex, ew) { \
            float w_ = __int_as_float(ew); \
            if (w_ != 0.f && mask_at(tmask, (ex) >> 4, mode)) { \
                v4f y_ = *(const v4f*)(labels + (ex) + cg4); \
                a4.x = fmaf(w_, y_.x, a4.x); a4.y = fmaf(w_, y_.y, a4.y); \
                a4.z = fmaf(w_, y_.z, a4.z); a4.w = fmaf(w_, y_.w, a4.w); } }
        ACC_LBL(u0.x, u0.y) ACC_LBL(u0.z, u0.w) ACC_LBL(u1.x, u1.y) ACC_LBL(u1.z, u1.w)
        #undef ACC_LBL
    }
    bfly4(a4);
    if (q == 0) {
        bool m = mask_at(tmask, row, mode);
        v4f lbl4 = *(const v4f*)(labels + t);      // t aligned (c == cg4)
        *(v4f*)(&Yout[t]) = m ? lbl4 : a4;
    }
}

__global__ __launch_bounds__(256) void spmv_step_t(const int2* __restrict__ pack,
                                                   const int* __restrict__ cnt,
                                                   const float* __restrict__ Yin,
                                                   const float* __restrict__ labels,
                                                   const void* __restrict__ tmask,
                                                   const int* __restrict__ flag,
                                                   float* __restrict__ Yout) {
    const int tid = threadIdx.x;
    const int row = blockIdx.x * RPB + (tid >> 4);
    const int c   = tid & 15;
    const int t   = row * CC + c;
    const int q   = c & 3;
    const int cg4 = c & 12;
    const int n = cnt[row];
    const int rounds = ((n + 15) & ~15) >> 4;
    const int pairs  = (rounds + 1) >> 1;
    const int4* pp = (const int4*)(pack + (size_t)row * CAP + q * 24);

    v4f a4 = acc_rounds<false>(pp, pairs, cg4, Yin);
    bfly4(a4);
    if (q == 0) {
        bool m = mask_at(tmask, row, *flag);
        v4f lbl4 = *(const v4f*)(labels + t);
        *(v4f*)(&Yout[t]) = m ? lbl4 : a4;
    }
}

__global__ __launch_bounds__(256) void spmv_harden_t(const int2* __restrict__ pack,
                                                     const int* __restrict__ cnt,
                                                     const float* __restrict__ Yin,
                                                     const float* __restrict__ labels,
                                                     const float* __restrict__ gumbel,
                                                     const void* __restrict__ tmask,
                                                     const int* __restrict__ flag,
                                                     float* __restrict__ Yout) {
    const int tid = threadIdx.x;
    const int row = blockIdx.x * RPB + (tid >> 4);
    const int c   = tid & 15;
    const int t   = row * CC + c;
    const int q   = c & 3;
    const int cg4 = c & 12;
    const int n = cnt[row];
    const int rounds = ((n + 15) & ~15) >> 4;
    const int pairs  = (rounds + 1) >> 1;
    const int4* pp = (const int4*)(pack + (size_t)row * CAP + q * 24);

    v4f a4 = acc_rounds<false>(pp, pairs, cg4, Yin);
    bfly4(a4);
    float acc = (q == 0) ? a4.x : (q == 1) ? a4.y : (q == 2) ? a4.z : a4.w;
    bool m = mask_at(tmask, row, *flag);
    float lbl = labels[t];
    float y10 = m ? lbl : acc;
    float l = y10 + gumbel[t];                     // TAU = 1
    float mx = l;
    for (int off = 8; off >= 1; off >>= 1) mx = fmaxf(mx, __shfl_xor(mx, off, 16));
    float e_ = expf(l - mx);
    float s = e_;
    for (int off = 8; off >= 1; off >>= 1) s += __shfl_xor(s, off, 16);
    float soft = e_ / s;
    float hard = (l == mx) ? 1.0f : 0.0f;
    float y = (hard + soft) - soft;                // faithful ST forward
    Yout[t] = m ? lbl : y;                         // scalar store (simple, safe)
}

__global__ __launch_bounds__(256) void mask_loss_t(const int2* __restrict__ pack,
                                                   const int* __restrict__ cnt,
                                                   const float* __restrict__ Y2,
                                                   const float* __restrict__ pseudo,
                                                   float* __restrict__ partial) {
    const int tid = threadIdx.x;
    const int row = blockIdx.x * RPB + (tid >> 4);
    const int c   = tid & 15;
    const int t   = row * CC + c;
    const int q   = c & 3;
    const int cg4 = c & 12;
    const int n = cnt[row];
    const int rounds = ((n + 15) & ~15) >> 4;
    const int pairs  = (rounds + 1) >> 1;
    const int4* pp = (const int4*)(pack + (size_t)row * CAP + q * 24);

    v4f a4 = acc_rounds<true>(pp, pairs, cg4, Y2);
    bfly4(a4);
    float acc = (q == 0) ? a4.x : (q == 1) ? a4.y : (q == 2) ? a4.z : a4.w;
    float rs = acc;                                // row sum (diag -> rs > 0)
    for (int off = 8; off >= 1; off >>= 1) rs += __shfl_xor(rs, off, 16);
    float d = acc / rs - pseudo[t];
    float contrib = d * d * (1.0f / (NN * CC));
    for (int off = 32; off >= 1; off >>= 1) contrib += __shfl_down(contrib, off, 64);
    __shared__ float sw[4];
    if ((tid & 63) == 0) sw[tid >> 6] = contrib;
    __syncthreads();
    if (tid == 0) partial[blockIdx.x] = sw[0] + sw[1] + sw[2] + sw[3];
}

__global__ void final_reduce(const float* __restrict__ partial, float* __restrict__ out) {
    float s = 0.0f;
    for (int i = threadIdx.x; i < NBLK; i += 256) s += partial[i];
    for (int off = 32; off >= 1; off >>= 1) s += __shfl_down(s, off, 64);
    __shared__ float sw[4];
    if ((threadIdx.x & 63) == 0) sw[threadIdx.x >> 6] = s;
    __syncthreads();
    if (threadIdx.x == 0) out[0] = sw[0] + sw[1] + sw[2] + sw[3];
}

extern "C" void kernel_launch(void* const* d_in, const int* in_sizes, int n_in,
                              void* d_out, int out_size, void* d_ws, size_t ws_size,
                              hipStream_t stream) {
    const float* adj    = (const float*)d_in[0];
    const float* labels = (const float*)d_in[1];
    const float* pseudo = (const float*)d_in[2];
    const float* gumbel = (const float*)d_in[3];
    const void*  tmask  = d_in[4];
    // d_in[5] = iter_step (10), d_in[6] = k_hop (1): fixed scalars in setup.

    char* ws = (char*)d_ws;
    int*   flag    = (int*)(ws + 0);                 // 64 B
    int*   cnt     = (int*)(ws + 64);                // 40,000 B
    int2*  pack    = (int2*)(ws + 40064);            // 7,680,000 B (16B-aligned)
    float* Ya      = (float*)(ws + 7720064);         // 640,000 B
    float* Yb      = (float*)(ws + 8360064);         // 640,000 B
    float* partial = (float*)(ws + 9000064);         // 2,560 B

    float* outp = (float*)d_out;

    // 13-dispatch chain: kernel boundaries are the inter-step barriers
    // (free coherence -> plain cached loads, full-grid occupancy per step).
    build_csr_t<<<CSRB + 1, 256, 0, stream>>>(adj, pack, cnt,
                                              (const unsigned int*)tmask, flag);
    spmv_first_t<<<NBLK, 256, 0, stream>>>(pack, cnt, labels, tmask, flag, Ya);
    float* cur = Ya;
    float* nxt = Yb;
    for (int it = 0; it < 8; ++it) {
        spmv_step_t<<<NBLK, 256, 0, stream>>>(pack, cnt, cur, labels, tmask, flag, nxt);
        float* tmp = cur; cur = nxt; nxt = tmp;
    }
    spmv_harden_t<<<NBLK, 256, 0, stream>>>(pack, cnt, cur, labels, gumbel, tmask, flag, nxt);
    mask_loss_t<<<NBLK, 256, 0, stream>>>(pack, cnt, nxt, pseudo, partial);
    final_reduce<<<1, 256, 0, stream>>>(partial, outp);
}